// Round 8
// baseline (180.509 us; speedup 1.0000x reference)
//
#include <hip/hip_runtime.h>
#include <hip/hip_bf16.h>
#include <stdint.h>

// Problem constants
#define NT 4096      // tokens
#define DM 320       // model dim
#define NH 8         // heads
#define DH 40        // head dim
#define DHP 64       // Q row stride (d 40..63 never written, never read)
#define KS 8         // split-K factor over the key dimension
#define QSCALE 0.22811013f  // (1/sqrt(40)) * log2(e): folded into Q so p = exp2(qk)
#define PSTR 68      // P-tile LDS row stride (ushorts): b64 8B-aligned, <=2-way banks
#define KFJB 640     // Kf shorts per 16-key block: 512 (k<32) + 128 (k=32..39, quad0)

typedef float f32x4 __attribute__((ext_vector_type(4)));
typedef __bf16 bf16x8 __attribute__((ext_vector_type(8)));

__device__ __forceinline__ unsigned short f2b(float f) {
  unsigned u = __builtin_bit_cast(unsigned, f);
  u += 0x7FFFu + ((u >> 16) & 1u);   // RNE
  return (unsigned short)(u >> 16);
}

__device__ __forceinline__ bf16x8 ld_bf8(const unsigned short* p) {
  uint4 v = *(const uint4*)p;        // 16B load
  return __builtin_bit_cast(bf16x8, v);
}

__device__ __forceinline__ f32x4 mfma16(bf16x8 a, bf16x8 b, f32x4 c) {
  return __builtin_amdgcn_mfma_f32_16x16x32_bf16(a, b, c, 0, 0, 0);
}

__device__ __forceinline__ float fexp2(float x) {
#if __has_builtin(__builtin_amdgcn_exp2f)
  return __builtin_amdgcn_exp2f(x);
#else
  float r; asm("v_exp_f32 %0, %1" : "=v"(r) : "v"(x)); return r;
#endif
}

// ---------------- kernel 1: prep (x->bf16 | signatures | weights->bf16^T) --------
// blocks 0..1279: x; 1280..1295: sig; 1296..1395: weights.
// Wt[1280][320]: rows 0..319 Wq^T, 320..639 Wk^T, 640..959 Wv^T, 960..1279 Wo^T.
__global__ __launch_bounds__(256) void prep_kernel(
    const float* __restrict__ x, const float* __restrict__ g,
    const float* __restrict__ Wq, const float* __restrict__ Wk,
    const float* __restrict__ Wv, const float* __restrict__ Wo,
    unsigned short* __restrict__ xb, unsigned char* __restrict__ sigb,
    unsigned short* __restrict__ Wt) {
  __shared__ __align__(16) unsigned short lt[64 * 72];
  const int b = blockIdx.x, t = threadIdx.x;
  if (b < 1280) {                       // ---- x -> bf16
    int i = (b * 256 + t) * 4;
    float4 v = *(const float4*)(x + i);
    ushort4 u;
    u.x = f2b(v.x); u.y = f2b(v.y); u.z = f2b(v.z); u.w = f2b(v.w);
    *(ushort4*)(xb + i) = u;
    return;
  }
  if (b < 1296) {                       // ---- phase signatures
    int i = (b - 1280) * 256 + t;
    unsigned s = 0;
    if (g[i] != 0.f)          s |= 1u;
    if (g[NT + i] != 0.f)     s |= 2u;
    if (g[2 * NT + i] != 0.f) s |= 4u;
    sigb[i] = (unsigned char)s;
    return;
  }
  // ---- weights -> bf16 transposed
  int bb = b - 1296;
  int kx = bb % 5, cy = bb / 5;         // kx: k-tile, cy: c-tile over 4 mats
  int cm = cy % 5;
  const float* src;
  int rowbase;
  if (cy < 5)       { src = Wq; rowbase = cm * 64; }
  else if (cy < 10) { src = Wk; rowbase = 320 + cm * 64; }
  else if (cy < 15) { src = Wv; rowbase = 640 + cm * 64; }
  else              { src = Wo; rowbase = 960 + cm * 64; }
  const int c0 = cm * 64;
  const int k0 = kx * 64;
#pragma unroll
  for (int i = 0; i < 4; ++i) {         // read 64k x 64c fp32, transpose to LDS
    int kr = (t >> 4) + i * 16, cc = (t & 15) * 4;
    float4 w4 = *(const float4*)&src[(size_t)(k0 + kr) * DM + c0 + cc];
    lt[(cc + 0) * 72 + kr] = f2b(w4.x);
    lt[(cc + 1) * 72 + kr] = f2b(w4.y);
    lt[(cc + 2) * 72 + kr] = f2b(w4.z);
    lt[(cc + 3) * 72 + kr] = f2b(w4.w);
  }
  __syncthreads();
#pragma unroll
  for (int i = 0; i < 2; ++i) {         // write 64c rows, k-contiguous
    int idx = t + i * 256, cl = idx >> 3, ch = idx & 7;
    *(uint4*)&Wt[(size_t)(rowbase + cl) * DM + k0 + ch * 8] =
        *(const uint4*)&lt[cl * 72 + ch * 8];
  }
}

// ---------------- kernel 2: fused QKV projection (LDS-free, frags from L2) -------
// Q: [h][n][DHP] bf16 pre-scaled by QSCALE, only d<40 written.
// Kf: compact frag-major per 16-key block (KFJB shorts): k<32 full, k 32..39 quad0.
// Vf: frag-major [h][jt=n/64][ot=d/16][c][quad][ln=d%16][e] (d 40..47 garbage).
__global__ __launch_bounds__(256, 4) void qkv_gemm(
    const unsigned short* __restrict__ xb, const unsigned short* __restrict__ Wt,
    unsigned short* __restrict__ Qb, unsigned short* __restrict__ Kf,
    unsigned short* __restrict__ Vf) {
  const int t = threadIdx.x;
  const int w = t >> 6, lane = t & 63, quad = lane >> 4, ln = lane & 15;
  const int m0 = blockIdx.x * 64;
  const int cy = blockIdx.y;                  // 0..14
  const int a = cy / 5;                       // 0=Q 1=K 2=V
  const int cc0 = (cy % 5) * 64;
  const unsigned short* Arow = xb + (size_t)(m0 + w * 16 + ln) * DM + quad * 8;
  const unsigned short* Brow = Wt + (size_t)(a * 320 + cc0 + ln) * DM + quad * 8;

  f32x4 acc[4] = {{0,0,0,0},{0,0,0,0},{0,0,0,0},{0,0,0,0}};
  for (int kc = 0; kc < 10; ++kc) {
    bf16x8 af = ld_bf8(Arow + kc * 32);
#pragma unroll
    for (int nt = 0; nt < 4; ++nt) {
      bf16x8 bf = ld_bf8(Brow + (size_t)nt * 16 * DM + kc * 32);
      acc[nt] = mfma16(af, bf, acc[nt]);
    }
  }
#pragma unroll
  for (int nt = 0; nt < 4; ++nt) {
#pragma unroll
    for (int r = 0; r < 4; ++r) {
      int row = m0 + w * 16 + quad * 4 + r;   // D row = quad*4+reg
      int cc = cc0 + nt * 16 + ln;            // D col = lane&15
      int h = cc / DH, d = cc % DH;
      if (a == 0) {
        Qb[((size_t)(h * NT + row)) * DHP + d] = f2b(acc[nt][r] * QSCALE);
      } else if (a == 1) {
        size_t base = ((size_t)h * 256 + (row >> 4)) * KFJB;
        size_t idx = (d < 32)
            ? base + (size_t)(d >> 3) * 128 + (size_t)(row & 15) * 8 + (d & 7)
            : base + 512 + (size_t)(row & 15) * 8 + (d - 32);
        Kf[idx] = f2b(acc[nt][r]);
      } else {
        size_t idx = (((((size_t)(h * 64 + (row >> 6)) * 3 + (d >> 4)) * 2 +
                        ((row >> 5) & 1)) * 4 + ((row >> 3) & 3)) * 16 +
                      (d & 15)) * 8 + (row & 7);
        Vf[idx] = f2b(acc[nt][r]);
      }
    }
  }
}

// ---------------- kernel 3: barrier-free masked attention ----------------
// grid (32 q-tiles of 128 rows, 8 heads, KS=8); block 256 = 4 waves x 32 q-rows.
// S^T = K*Q^T (A=K frags from compact Kf); P via wave-private LDS round-trip;
// O^T = V^T*P (A=V frags from Vf). NO __syncthreads anywhere.
__global__ __launch_bounds__(256, 4) void attn_kernel(
    const unsigned short* __restrict__ Qb, const unsigned short* __restrict__ Kf,
    const unsigned short* __restrict__ Vf, const unsigned char* __restrict__ sigb,
    unsigned short* __restrict__ Opart, float* __restrict__ Lpart) {
  __shared__ __align__(16) unsigned short pt[4][32 * PSTR];   // per-wave P^T 17408 B
  const int t = threadIdx.x;
  const int w = t >> 6, lane = t & 63, quad = lane >> 4, ln = lane & 15;
  const int h = blockIdx.y, qt = blockIdx.x, sp = blockIdx.z;
  const int qrow = qt * 128 + w * 32;
  const int j0 = sp * 8;

  const unsigned short* Kfh = Kf + (size_t)h * 256 * KFJB;
  const unsigned short* Vfh = Vf + (size_t)h * 196608;   // 64 jt * 3ot * 2c * 512
  unsigned short* ptw = pt[w];
  const uint4 z4 = {0, 0, 0, 0};

  bf16x8 qa[2][2];
  unsigned sq[2], uq[2];
  float rs[2] = {0.f, 0.f};
  f32x4 o[3][2] = {{{0,0,0,0},{0,0,0,0}},{{0,0,0,0},{0,0,0,0}},{{0,0,0,0},{0,0,0,0}}};

#pragma unroll
  for (int tq = 0; tq < 2; ++tq) {
    int row = qrow + tq * 16 + ln;
    const unsigned short* Qp = Qb + ((size_t)h * NT + row) * DHP;
    qa[tq][0] = ld_bf8(Qp + quad * 8);                 // k 0..31
    uint4 q1 = z4;                                     // k 32..63: only quad0 real
    if (quad == 0) q1 = *(const uint4*)(Qp + 32 + ln * 0 + quad * 8 + 0);
    qa[tq][1] = __builtin_bit_cast(bf16x8, q1);
    unsigned s = sigb[row];
    sq[tq] = s;
    uq[tq] = (s == 0u) ? 1u : 0u;
    if (s == 0u) {                 // uniform row: logits exactly 0 -> p = 1
      qa[tq][0] = __builtin_bit_cast(bf16x8, z4);
      qa[tq][1] = __builtin_bit_cast(bf16x8, z4);
    }
  }

  for (int jt = j0; jt < j0 + 8; ++jt) {
    // K fragments from compact Kf: 4 x 1KB + 4 x 256B (quad0) coalesced loads
    uint4 kfr0[4], kfr1[4];
#pragma unroll
    for (int nt = 0; nt < 4; ++nt) {
      const unsigned short* kb = Kfh + (size_t)(jt * 4 + nt) * KFJB;
      kfr0[nt] = *(const uint4*)(kb + lane * 8);
      kfr1[nt] = z4;
      if (lane < 16) kfr1[nt] = *(const uint4*)(kb + 512 + lane * 8);
    }

#pragma unroll
    for (int nt = 0; nt < 4; ++nt) {
      bf16x8 ka0 = __builtin_bit_cast(bf16x8, kfr0[nt]);
      bf16x8 ka1 = __builtin_bit_cast(bf16x8, kfr1[nt]);
      unsigned spj = *(const unsigned*)(sigb + jt * 64 + nt * 16 + quad * 4);
#pragma unroll
      for (int tq = 0; tq < 2; ++tq) {
        f32x4 acc = {0.f, 0.f, 0.f, 0.f};
        acc = mfma16(ka0, qa[tq][0], acc);    // S^T[j=nt*16+quad*4+r][m=ln]
        acc = mfma16(ka1, qa[tq][1], acc);
        unsigned u[4];
#pragma unroll
        for (int r = 0; r < 4; ++r) {
          unsigned skr = (spj >> (8 * r)) & 255u;
          unsigned msk = (sq[tq] & skr) | uq[tq];
          float p = msk ? fexp2(acc[r]) : 0.f;
          unsigned ut = __builtin_bit_cast(unsigned, p) & 0xffff0000u; // trunc bf16
          rs[tq] += __builtin_bit_cast(float, ut);  // denom == numerator weights
          u[r] = ut;
        }
        uint2 pk;
        pk.x = (u[0] >> 16) | u[1];           // bf16 pair (j+0, j+1)
        pk.y = (u[2] >> 16) | u[3];           // bf16 pair (j+2, j+3)
        *(uint2*)&ptw[(tq * 16 + ln) * PSTR + nt * 16 + quad * 4] = pk;  // b64
      }
    }
    // V fragments: 6 coalesced 1KB wave loads (consumed after P round-trip)
    uint4 vfr[6];
#pragma unroll
    for (int ot = 0; ot < 3; ++ot)
#pragma unroll
      for (int c = 0; c < 2; ++c)
        vfr[ot * 2 + c] =
            *(const uint4*)(Vfh + ((size_t)((jt * 3 + ot) * 2 + c)) * 512 + lane * 8);

    asm volatile("s_waitcnt lgkmcnt(0)" ::: "memory");   // wave-private P RAW
    bf16x8 pb[2][2];
#pragma unroll
    for (int tq = 0; tq < 2; ++tq) {
      pb[tq][0] = ld_bf8(&ptw[(tq * 16 + ln) * PSTR + quad * 8]);
      pb[tq][1] = ld_bf8(&ptw[(tq * 16 + ln) * PSTR + 32 + quad * 8]);
    }
#pragma unroll
    for (int ot = 0; ot < 3; ++ot) {
      bf16x8 va0 = __builtin_bit_cast(bf16x8, vfr[ot * 2]);
      bf16x8 va1 = __builtin_bit_cast(bf16x8, vfr[ot * 2 + 1]);
#pragma unroll
      for (int tq = 0; tq < 2; ++tq) {
        o[ot][tq] = mfma16(va0, pb[tq][0], o[ot][tq]);   // O^T[d][m]
        o[ot][tq] = mfma16(va1, pb[tq][1], o[ot][tq]);
      }
    }
  }

  // epilogue: reduce row-sum across quads; store bf16 partials [sp][row][DM]
#pragma unroll
  for (int tq = 0; tq < 2; ++tq) {
    float s = rs[tq];
    s += __shfl_xor(s, 16);
    s += __shfl_xor(s, 32);
    int row = qrow + tq * 16 + ln;
    unsigned short* Op = Opart + (size_t)(sp * NT + row) * DM + h * DH;
#pragma unroll
    for (int ot = 0; ot < 3; ++ot) {
      int d0 = ot * 16 + quad * 4;
      if (d0 < DH) {
        uint2 pk;
        pk.x = (unsigned)f2b(o[ot][tq][0]) | ((unsigned)f2b(o[ot][tq][1]) << 16);
        pk.y = (unsigned)f2b(o[ot][tq][2]) | ((unsigned)f2b(o[ot][tq][3]) << 16);
        *(uint2*)(Op + d0) = pk;
      }
    }
    if (lane < 16)
      Lpart[sp * NT + row] = s;
  }
}

// ---------------- kernel 4: out projection + split-K combine + bias ----------------
__global__ __launch_bounds__(256, 4) void out_gemm(
    const unsigned short* __restrict__ Opart, const float* __restrict__ Lpart,
    const unsigned short* __restrict__ Wt, const float* __restrict__ bo,
    float* __restrict__ out) {
  const int t = threadIdx.x;
  const int w = t >> 6, lane = t & 63, quad = lane >> 4, ln = lane & 15;
  const int m0 = blockIdx.x * 64;
  const int cc0 = blockIdx.y * 64;
  const int arow = m0 + w * 16 + ln;
  float ls = 0.f;
#pragma unroll
  for (int sp = 0; sp < KS; ++sp) ls += Lpart[sp * NT + arow];
  const float inv = 1.f / ls;
  const unsigned short* Brow = Wt + (size_t)(960 + cc0 + ln) * DM + quad * 8;

  f32x4 acc[4] = {{0,0,0,0},{0,0,0,0},{0,0,0,0},{0,0,0,0}};
  for (int kc = 0; kc < 10; ++kc) {
    int c8 = kc * 32 + quad * 8;
    float s8[8] = {0, 0, 0, 0, 0, 0, 0, 0};
#pragma unroll
    for (int sp = 0; sp < KS; ++sp) {
      uint4 v = *(const uint4*)(Opart + (size_t)(sp * NT + arow) * DM + c8);
      unsigned vv[4] = {v.x, v.y, v.z, v.w};
#pragma unroll
      for (int j = 0; j < 4; ++j) {
        s8[2 * j]     += __builtin_bit_cast(float, vv[j] << 16);
        s8[2 * j + 1] += __builtin_bit_cast(float, vv[j] & 0xffff0000u);
      }
    }
    unsigned short af8[8];
#pragma unroll
    for (int j = 0; j < 8; ++j) af8[j] = f2b(s8[j] * inv);
    bf16x8 af = ld_bf8(af8);
#pragma unroll
    for (int nt = 0; nt < 4; ++nt) {
      bf16x8 bf = ld_bf8(Brow + (size_t)nt * 16 * DM + kc * 32);
      acc[nt] = mfma16(af, bf, acc[nt]);
    }
  }
#pragma unroll
  for (int nt = 0; nt < 4; ++nt)
#pragma unroll
    for (int r = 0; r < 4; ++r) {
      int row = m0 + w * 16 + quad * 4 + r;
      int col = cc0 + nt * 16 + ln;
      out[(size_t)row * DM + col] = acc[nt][r] + bo[col];
    }
}

// ---------------- launcher ----------------
extern "C" void kernel_launch(void* const* d_in, const int* in_sizes, int n_in,
                              void* d_out, int out_size, void* d_ws, size_t ws_size,
                              hipStream_t stream) {
  const float* x  = (const float*)d_in[0];
  const float* g  = (const float*)d_in[1];
  const float* Wq = (const float*)d_in[2];
  const float* Wk = (const float*)d_in[3];
  const float* Wv = (const float*)d_in[4];
  const float* Wo = (const float*)d_in[5];
  const float* bo = (const float*)d_in[6];
  float* out = (float*)d_out;

  char* ws = (char*)d_ws;
  const size_t SIG_OFF = 0;
  const size_t XB_OFF  = 16384;
  const size_t WT_OFF  = XB_OFF + (size_t)NT * DM * 2;              // +2.62 MB
  const size_t QB_OFF  = WT_OFF + (size_t)1280 * DM * 2;            // +0.82 MB
  const size_t KF_OFF  = QB_OFF + (size_t)NH * NT * DHP * 2;        // +4.19 MB
  const size_t VF_OFF  = KF_OFF + (size_t)NH * 256 * KFJB * 2;      // +2.62 MB
  const size_t OP_OFF  = VF_OFF + (size_t)NH * 196608 * 2;          // +3.15 MB
  const size_t LP_OFF  = OP_OFF + (size_t)KS * NT * DM * 2;         // +20.97 MB
  unsigned char* sigb  = (unsigned char*)(ws + SIG_OFF);
  unsigned short* xb   = (unsigned short*)(ws + XB_OFF);
  unsigned short* Wt   = (unsigned short*)(ws + WT_OFF);
  unsigned short* Qb   = (unsigned short*)(ws + QB_OFF);
  unsigned short* Kf   = (unsigned short*)(ws + KF_OFF);
  unsigned short* Vf   = (unsigned short*)(ws + VF_OFF);
  unsigned short* Opart= (unsigned short*)(ws + OP_OFF);
  float* Lpart         = (float*)(ws + LP_OFF);

  // No memset: Q/K zero-halves are synthesized in-register in attn (quad-select);
  // Vf d=40..47 garbage feeds only discarded outputs (0xAA bf16 is tiny, no NaN).
  prep_kernel<<<1396, 256, 0, stream>>>(x, g, Wq, Wk, Wv, Wo, xb, sigb, Wt);
  qkv_gemm<<<dim3(64, 15), 256, 0, stream>>>(xb, Wt, Qb, Kf, Vf);
  attn_kernel<<<dim3(32, NH, KS), 256, 0, stream>>>(Qb, Kf, Vf, sigb, Opart, Lpart);
  out_gemm<<<dim3(64, 5), 256, 0, stream>>>(Opart, Lpart, Wt, bo, out);
}

// Round 9
// 162.951 us; speedup vs baseline: 1.1077x; 1.1077x over previous
//
#include <hip/hip_runtime.h>
#include <hip/hip_bf16.h>
#include <stdint.h>

// Problem constants
#define NT 4096      // tokens
#define DM 320       // model dim
#define NH 8         // heads
#define DH 40        // head dim
#define DHP 64       // Q row stride (d 40..63 never written; zero-synth in attn)
#define KS 4         // split-K factor over the key dimension
#define QSCALE 0.22811013f  // (1/sqrt(40)) * log2(e): folded into Q so p = exp2(qk)
#define PSTR 68      // P-tile LDS row stride (ushorts): b64 8B-aligned, <=2-way banks
#define KFJB 640     // Kf shorts per 16-key block: 512 (k<32) + 128 (k=32..39, quad0)

typedef float f32x4 __attribute__((ext_vector_type(4)));
typedef __bf16 bf16x8 __attribute__((ext_vector_type(8)));

__device__ __forceinline__ unsigned short f2b(float f) {
  unsigned u = __builtin_bit_cast(unsigned, f);
  u += 0x7FFFu + ((u >> 16) & 1u);   // RNE
  return (unsigned short)(u >> 16);
}

__device__ __forceinline__ bf16x8 ld_bf8(const unsigned short* p) {
  uint4 v = *(const uint4*)p;        // 16B load
  return __builtin_bit_cast(bf16x8, v);
}

__device__ __forceinline__ f32x4 mfma16(bf16x8 a, bf16x8 b, f32x4 c) {
  return __builtin_amdgcn_mfma_f32_16x16x32_bf16(a, b, c, 0, 0, 0);
}

__device__ __forceinline__ float fexp2(float x) {
#if __has_builtin(__builtin_amdgcn_exp2f)
  return __builtin_amdgcn_exp2f(x);
#else
  float r; asm("v_exp_f32 %0, %1" : "=v"(r) : "v"(x)); return r;
#endif
}

// ---------------- kernel 1: prep (x->bf16 | sig | weights->bf16^T | V-ones) ------
// blocks 0..1279: x; 1280..1295: sig; 1296..1395: weights; 1396..1523: Vf ones.
// Wt[1280][320]: rows 0..319 Wq^T, 320..639 Wk^T, 640..959 Wv^T, 960..1279 Wo^T.
__global__ __launch_bounds__(256) void prep_kernel(
    const float* __restrict__ x, const float* __restrict__ g,
    const float* __restrict__ Wq, const float* __restrict__ Wk,
    const float* __restrict__ Wv, const float* __restrict__ Wo,
    unsigned short* __restrict__ xb, unsigned char* __restrict__ sigb,
    unsigned short* __restrict__ Wt, unsigned short* __restrict__ Vf) {
  __shared__ __align__(16) unsigned short lt[64 * 72];
  const int b = blockIdx.x, t = threadIdx.x;
  if (b < 1280) {                       // ---- x -> bf16
    int i = (b * 256 + t) * 4;
    float4 v = *(const float4*)(x + i);
    ushort4 u;
    u.x = f2b(v.x); u.y = f2b(v.y); u.z = f2b(v.z); u.w = f2b(v.w);
    *(ushort4*)(xb + i) = u;
    return;
  }
  if (b < 1296) {                       // ---- phase signatures
    int i = (b - 1280) * 256 + t;
    unsigned s = 0;
    if (g[i] != 0.f)          s |= 1u;
    if (g[NT + i] != 0.f)     s |= 2u;
    if (g[2 * NT + i] != 0.f) s |= 4u;
    sigb[i] = (unsigned char)s;
    return;
  }
  if (b >= 1396) {                      // ---- Vf ones column at d=40 (rs via MFMA)
    int gid = (b - 1396) * 256 + t;     // < NH*NT = 32768
    int h = gid >> 12, row = gid & 4095;
    size_t idx = (((((size_t)(h * 64 + (row >> 6)) * 3 + 2) * 2 +
                    ((row >> 5) & 1)) * 4 + ((row >> 3) & 3)) * 16 + 8) * 8 +
                 (row & 7);
    Vf[idx] = 0x3F80;                   // bf16 1.0
    return;
  }
  // ---- weights -> bf16 transposed
  int bb = b - 1296;
  int kx = bb % 5, cy = bb / 5;         // kx: k-tile, cy: c-tile over 4 mats
  int cm = cy % 5;
  const float* src;
  int rowbase;
  if (cy < 5)       { src = Wq; rowbase = cm * 64; }
  else if (cy < 10) { src = Wk; rowbase = 320 + cm * 64; }
  else if (cy < 15) { src = Wv; rowbase = 640 + cm * 64; }
  else              { src = Wo; rowbase = 960 + cm * 64; }
  const int c0 = cm * 64;
  const int k0 = kx * 64;
#pragma unroll
  for (int i = 0; i < 4; ++i) {         // read 64k x 64c fp32, transpose to LDS
    int kr = (t >> 4) + i * 16, cc = (t & 15) * 4;
    float4 w4 = *(const float4*)&src[(size_t)(k0 + kr) * DM + c0 + cc];
    lt[(cc + 0) * 72 + kr] = f2b(w4.x);
    lt[(cc + 1) * 72 + kr] = f2b(w4.y);
    lt[(cc + 2) * 72 + kr] = f2b(w4.z);
    lt[(cc + 3) * 72 + kr] = f2b(w4.w);
  }
  __syncthreads();
#pragma unroll
  for (int i = 0; i < 2; ++i) {         // write 64c rows, k-contiguous
    int idx = t + i * 256, cl = idx >> 3, ch = idx & 7;
    *(uint4*)&Wt[(size_t)(rowbase + cl) * DM + k0 + ch * 8] =
        *(const uint4*)&lt[cl * 72 + ch * 8];
  }
}

// ---------------- kernel 2: fused QKV projection (LDS-free, frags from L2) -------
// Q: [h][n][DHP] bf16 pre-scaled by QSCALE, only d<40 written.
// Kf: compact frag-major per 16-key block (KFJB shorts): k<32 full, k 32..39 quad0.
// Vf: frag-major [h][jt=n/64][ot=d/16][c][quad][ln=d%16][e] (d<40; d=40 = prep ones).
__global__ __launch_bounds__(256, 4) void qkv_gemm(
    const unsigned short* __restrict__ xb, const unsigned short* __restrict__ Wt,
    unsigned short* __restrict__ Qb, unsigned short* __restrict__ Kf,
    unsigned short* __restrict__ Vf) {
  const int t = threadIdx.x;
  const int w = t >> 6, lane = t & 63, quad = lane >> 4, ln = lane & 15;
  const int m0 = blockIdx.x * 64;
  const int cy = blockIdx.y;                  // 0..14
  const int a = cy / 5;                       // 0=Q 1=K 2=V
  const int cc0 = (cy % 5) * 64;
  const unsigned short* Arow = xb + (size_t)(m0 + w * 16 + ln) * DM + quad * 8;
  const unsigned short* Brow = Wt + (size_t)(a * 320 + cc0 + ln) * DM + quad * 8;

  f32x4 acc[4] = {{0,0,0,0},{0,0,0,0},{0,0,0,0},{0,0,0,0}};
  for (int kc = 0; kc < 10; ++kc) {
    bf16x8 af = ld_bf8(Arow + kc * 32);
#pragma unroll
    for (int nt = 0; nt < 4; ++nt) {
      bf16x8 bf = ld_bf8(Brow + (size_t)nt * 16 * DM + kc * 32);
      acc[nt] = mfma16(af, bf, acc[nt]);
    }
  }
#pragma unroll
  for (int nt = 0; nt < 4; ++nt) {
#pragma unroll
    for (int r = 0; r < 4; ++r) {
      int row = m0 + w * 16 + quad * 4 + r;   // D row = quad*4+reg
      int cc = cc0 + nt * 16 + ln;            // D col = lane&15
      int h = cc / DH, d = cc % DH;
      if (a == 0) {
        Qb[((size_t)(h * NT + row)) * DHP + d] = f2b(acc[nt][r] * QSCALE);
      } else if (a == 1) {
        size_t base = ((size_t)h * 256 + (row >> 4)) * KFJB;
        size_t idx = (d < 32)
            ? base + (size_t)(d >> 3) * 128 + (size_t)(row & 15) * 8 + (d & 7)
            : base + 512 + (size_t)(row & 15) * 8 + (d - 32);
        Kf[idx] = f2b(acc[nt][r]);
      } else {
        size_t idx = (((((size_t)(h * 64 + (row >> 6)) * 3 + (d >> 4)) * 2 +
                        ((row >> 5) & 1)) * 4 + ((row >> 3) & 3)) * 16 +
                      (d & 15)) * 8 + (row & 7);
        Vf[idx] = f2b(acc[nt][r]);
      }
    }
  }
}

// ---------------- kernel 3: barrier-free masked attention ----------------
// grid (32 q-tiles of 128 rows, 8 heads, KS=4); block 256 = 4 waves x 32 q-rows.
// S^T = K*Q^T (A=K frags from compact Kf); masked exp via packed-byte signature
// (masked -> exp2(-3e38) = 0); P via wave-private LDS round-trip; O^T = V^T*P
// with a ones-column at d=40 giving the row-sum denominator for free.
__global__ __launch_bounds__(256, 4) void attn_kernel(
    const unsigned short* __restrict__ Qb, const unsigned short* __restrict__ Kf,
    const unsigned short* __restrict__ Vf, const unsigned char* __restrict__ sigb,
    unsigned short* __restrict__ Opart, float* __restrict__ Lpart) {
  __shared__ __align__(16) unsigned short pt[4][32 * PSTR];   // per-wave P^T 17408 B
  const int t = threadIdx.x;
  const int w = t >> 6, lane = t & 63, quad = lane >> 4, ln = lane & 15;
  const int h = blockIdx.y, qt = blockIdx.x, sp = blockIdx.z;
  const int qrow = qt * 128 + w * 32;
  const int j0 = sp * 16;

  const unsigned short* Kfh = Kf + (size_t)h * 256 * KFJB;
  const unsigned short* Vfh = Vf + (size_t)h * 196608;   // 64 jt * 3ot * 2c * 512
  unsigned short* ptw = pt[w];
  const uint4 z4 = {0, 0, 0, 0};

  bf16x8 qa[2][2];
  unsigned sqx4[2], uqx4[2];
  f32x4 o[3][2] = {{{0,0,0,0},{0,0,0,0}},{{0,0,0,0},{0,0,0,0}},{{0,0,0,0},{0,0,0,0}}};

#pragma unroll
  for (int tq = 0; tq < 2; ++tq) {
    int row = qrow + tq * 16 + ln;
    const unsigned short* Qp = Qb + ((size_t)h * NT + row) * DHP;
    qa[tq][0] = ld_bf8(Qp + quad * 8);                 // k 0..31
    uint4 q1 = z4;                                     // k 32..63: only quad0 real
    if (quad == 0) q1 = *(const uint4*)(Qp + 32);
    qa[tq][1] = __builtin_bit_cast(bf16x8, q1);
    unsigned s = sigb[row];
    sqx4[tq] = s * 0x01010101u;
    uqx4[tq] = (s == 0u) ? 0xFFFFFFFFu : 0u;
    if (s == 0u) {                 // uniform row: logits exactly 0 -> p = 1
      qa[tq][0] = __builtin_bit_cast(bf16x8, z4);
      qa[tq][1] = __builtin_bit_cast(bf16x8, z4);
    }
  }

  for (int jt = j0; jt < j0 + 16; ++jt) {
    // K fragments from compact Kf: 4 x 1KB + 4 x 256B (quad0) coalesced loads
    uint4 kfr0[4], kfr1[4];
#pragma unroll
    for (int nt = 0; nt < 4; ++nt) {
      const unsigned short* kb = Kfh + (size_t)(jt * 4 + nt) * KFJB;
      kfr0[nt] = *(const uint4*)(kb + lane * 8);
      kfr1[nt] = z4;
      if (lane < 16) kfr1[nt] = *(const uint4*)(kb + 512 + lane * 8);
    }

#pragma unroll
    for (int nt = 0; nt < 4; ++nt) {
      bf16x8 ka0 = __builtin_bit_cast(bf16x8, kfr0[nt]);
      bf16x8 ka1 = __builtin_bit_cast(bf16x8, kfr1[nt]);
      unsigned spj = *(const unsigned*)(sigb + jt * 64 + nt * 16 + quad * 4);
#pragma unroll
      for (int tq = 0; tq < 2; ++tq) {
        f32x4 acc = {0.f, 0.f, 0.f, 0.f};
        acc = mfma16(ka0, qa[tq][0], acc);    // S^T[j=nt*16+quad*4+r][m=ln]
        acc = mfma16(ka1, qa[tq][1], acc);
        unsigned m4 = (spj & sqx4[tq]) | uqx4[tq];   // byte r != 0 <=> unmasked
        unsigned u[4];
#pragma unroll
        for (int r = 0; r < 4; ++r) {
          unsigned mb = (m4 >> (8 * r)) & 255u;      // v_bfe
          float am = mb ? acc[r] : -3.0e38f;         // masked -> exp2 = 0
          u[r] = __builtin_bit_cast(unsigned, fexp2(am));
        }
        uint2 pk;                                    // truncate-to-bf16 pack
        pk.x = (u[0] >> 16) | (u[1] & 0xffff0000u);  // (j+0, j+1)
        pk.y = (u[2] >> 16) | (u[3] & 0xffff0000u);  // (j+2, j+3)
        *(uint2*)&ptw[(tq * 16 + ln) * PSTR + nt * 16 + quad * 4] = pk;  // b64
      }
    }
    // V fragments: 6 coalesced 1KB wave loads (consumed after P round-trip)
    uint4 vfr[6];
#pragma unroll
    for (int ot = 0; ot < 3; ++ot)
#pragma unroll
      for (int c = 0; c < 2; ++c)
        vfr[ot * 2 + c] =
            *(const uint4*)(Vfh + ((size_t)((jt * 3 + ot) * 2 + c)) * 512 + lane * 8);

    asm volatile("s_waitcnt lgkmcnt(0)" ::: "memory");   // wave-private P RAW
    bf16x8 pb[2][2];
#pragma unroll
    for (int tq = 0; tq < 2; ++tq) {
      pb[tq][0] = ld_bf8(&ptw[(tq * 16 + ln) * PSTR + quad * 8]);
      pb[tq][1] = ld_bf8(&ptw[(tq * 16 + ln) * PSTR + 32 + quad * 8]);
    }
#pragma unroll
    for (int ot = 0; ot < 3; ++ot) {
      bf16x8 va0 = __builtin_bit_cast(bf16x8, vfr[ot * 2]);
      bf16x8 va1 = __builtin_bit_cast(bf16x8, vfr[ot * 2 + 1]);
#pragma unroll
      for (int tq = 0; tq < 2; ++tq) {
        o[ot][tq] = mfma16(va0, pb[tq][0], o[ot][tq]);   // O^T[d][m]
        o[ot][tq] = mfma16(va1, pb[tq][1], o[ot][tq]);
      }
    }
  }

  // epilogue: O^T d = ot*16+quad*4+r, m = ln; d=40 (ot=2,quad=2,r=0) is the row-sum
#pragma unroll
  for (int tq = 0; tq < 2; ++tq) {
    int row = qrow + tq * 16 + ln;
    unsigned short* Op = Opart + (size_t)(sp * NT + row) * DM + h * DH;
#pragma unroll
    for (int ot = 0; ot < 3; ++ot) {
      int d0 = ot * 16 + quad * 4;
      if (d0 < DH) {
        uint2 pk;
        pk.x = (unsigned)f2b(o[ot][tq][0]) | ((unsigned)f2b(o[ot][tq][1]) << 16);
        pk.y = (unsigned)f2b(o[ot][tq][2]) | ((unsigned)f2b(o[ot][tq][3]) << 16);
        *(uint2*)(Op + d0) = pk;
      }
    }
    if (quad == 2)
      Lpart[sp * NT + row] = o[2][tq][0];   // MFMA-computed denominator
  }
}

// ---------------- kernel 4: out projection + split-K combine + bias ----------------
__global__ __launch_bounds__(256, 4) void out_gemm(
    const unsigned short* __restrict__ Opart, const float* __restrict__ Lpart,
    const unsigned short* __restrict__ Wt, const float* __restrict__ bo,
    float* __restrict__ out) {
  const int t = threadIdx.x;
  const int w = t >> 6, lane = t & 63, quad = lane >> 4, ln = lane & 15;
  const int m0 = blockIdx.x * 64;
  const int cc0 = blockIdx.y * 64;
  const int arow = m0 + w * 16 + ln;
  float ls = 0.f;
#pragma unroll
  for (int sp = 0; sp < KS; ++sp) ls += Lpart[sp * NT + arow];
  const float inv = 1.f / ls;
  const unsigned short* Brow = Wt + (size_t)(960 + cc0 + ln) * DM + quad * 8;

  f32x4 acc[4] = {{0,0,0,0},{0,0,0,0},{0,0,0,0},{0,0,0,0}};
  for (int kc = 0; kc < 10; ++kc) {
    int c8 = kc * 32 + quad * 8;
    float s8[8] = {0, 0, 0, 0, 0, 0, 0, 0};
#pragma unroll
    for (int sp = 0; sp < KS; ++sp) {
      uint4 v = *(const uint4*)(Opart + (size_t)(sp * NT + arow) * DM + c8);
      unsigned vv[4] = {v.x, v.y, v.z, v.w};
#pragma unroll
      for (int j = 0; j < 4; ++j) {
        s8[2 * j]     += __builtin_bit_cast(float, vv[j] << 16);
        s8[2 * j + 1] += __builtin_bit_cast(float, vv[j] & 0xffff0000u);
      }
    }
    unsigned short af8[8];
#pragma unroll
    for (int j = 0; j < 8; ++j) af8[j] = f2b(s8[j] * inv);
    bf16x8 af = ld_bf8(af8);
#pragma unroll
    for (int nt = 0; nt < 4; ++nt) {
      bf16x8 bf = ld_bf8(Brow + (size_t)nt * 16 * DM + kc * 32);
      acc[nt] = mfma16(af, bf, acc[nt]);
    }
  }
#pragma unroll
  for (int nt = 0; nt < 4; ++nt)
#pragma unroll
    for (int r = 0; r < 4; ++r) {
      int row = m0 + w * 16 + quad * 4 + r;
      int col = cc0 + nt * 16 + ln;
      out[(size_t)row * DM + col] = acc[nt][r] + bo[col];
    }
}

// ---------------- launcher ----------------
extern "C" void kernel_launch(void* const* d_in, const int* in_sizes, int n_in,
                              void* d_out, int out_size, void* d_ws, size_t ws_size,
                              hipStream_t stream) {
  const float* x  = (const float*)d_in[0];
  const float* g  = (const float*)d_in[1];
  const float* Wq = (const float*)d_in[2];
  const float* Wk = (const float*)d_in[3];
  const float* Wv = (const float*)d_in[4];
  const float* Wo = (const float*)d_in[5];
  const float* bo = (const float*)d_in[6];
  float* out = (float*)d_out;

  char* ws = (char*)d_ws;
  const size_t SIG_OFF = 0;
  const size_t XB_OFF  = 16384;
  const size_t WT_OFF  = XB_OFF + (size_t)NT * DM * 2;              // +2.62 MB
  const size_t QB_OFF  = WT_OFF + (size_t)1280 * DM * 2;            // +0.82 MB
  const size_t KF_OFF  = QB_OFF + (size_t)NH * NT * DHP * 2;        // +4.19 MB
  const size_t VF_OFF  = KF_OFF + (size_t)NH * 256 * KFJB * 2;      // +2.62 MB
  const size_t OP_OFF  = VF_OFF + (size_t)NH * 196608 * 2;          // +3.15 MB
  const size_t LP_OFF  = OP_OFF + (size_t)KS * NT * DM * 2;         // +10.49 MB
  unsigned char* sigb  = (unsigned char*)(ws + SIG_OFF);
  unsigned short* xb   = (unsigned short*)(ws + XB_OFF);
  unsigned short* Wt   = (unsigned short*)(ws + WT_OFF);
  unsigned short* Qb   = (unsigned short*)(ws + QB_OFF);
  unsigned short* Kf   = (unsigned short*)(ws + KF_OFF);
  unsigned short* Vf   = (unsigned short*)(ws + VF_OFF);
  unsigned short* Opart= (unsigned short*)(ws + OP_OFF);
  float* Lpart         = (float*)(ws + LP_OFF);

  // No memset: Q/K zero-halves synthesized in-register in attn; Vf d=40 ones
  // written by prep; Vf d=41..47 garbage feeds only unstored lanes (no NaN).
  prep_kernel<<<1524, 256, 0, stream>>>(x, g, Wq, Wk, Wv, Wo, xb, sigb, Wt, Vf);
  qkv_gemm<<<dim3(64, 15), 256, 0, stream>>>(xb, Wt, Qb, Kf, Vf);
  attn_kernel<<<dim3(32, NH, KS), 256, 0, stream>>>(Qb, Kf, Vf, sigb, Opart, Lpart);
  out_gemm<<<dim3(64, 5), 256, 0, stream>>>(Opart, Lpart, Wt, bo, out);
}